// Round 5
// baseline (1066.984 us; speedup 1.0000x reference)
//
#include <hip/hip_runtime.h>
#include <cfloat>

#define NB   8
#define NC   64
#define NPTS 4096
#define KNN  20
#define CO   64

typedef __attribute__((ext_vector_type(8))) short bf16x8;
typedef __attribute__((ext_vector_type(4))) float f32x4;

#define MFMA(a, b, c) __builtin_amdgcn_mfma_f32_16x16x32_bf16(a, b, c, 0, 0, 0)

// ---------------------------------------------------------------------------
// bf16 helpers (RNE, bit-level; no NaN in this workload)
// ---------------------------------------------------------------------------
__device__ __forceinline__ unsigned short f2bf_rne(float f) {
    unsigned int u = __float_as_uint(f);
    unsigned int r = (u + 0x7FFFu + ((u >> 16) & 1u)) >> 16;
    return (unsigned short)r;
}
__device__ __forceinline__ float bf2f(unsigned short h) {
    return __uint_as_float(((unsigned int)h) << 16);
}

// monotone f32 <-> u32 order-preserving transform
__device__ __forceinline__ unsigned int flip_f(float s) {
    unsigned int b = __float_as_uint(s);
    return (b & 0x80000000u) ? ~b : (b | 0x80000000u);
}
__device__ __forceinline__ float unflip_f(unsigned int u) {
    unsigned int b = (u & 0x80000000u) ? (u ^ 0x80000000u) : ~u;
    return __uint_as_float(b);
}
// key packing: lexicographic (s, idx) ascending == u64 ascending
__device__ __forceinline__ unsigned long long pack_key(float s, int m) {
    return (((unsigned long long)flip_f(s)) << 32) | (unsigned int)m;
}

// ---------------------------------------------------------------------------
// Kernel P1: split x into bf16 triple (h,m,l), INTERLEAVED per point:
// xs[g][0..63]=h, [64..127]=m, [128..191]=l.  x = h+m+l+eps, |eps|<=2^-27|x|.
// ---------------------------------------------------------------------------
__global__ __launch_bounds__(256, 4) void split_kernel(
    const float* __restrict__ x, unsigned short* __restrict__ xs,
    float* __restrict__ xx)
{
    int g = blockIdx.x * 256 + threadIdx.x;        // global point
    int b = g >> 12, n = g & 4095;
    const float* xb = x + ((size_t)b << 18) + n;   // x[b][c][n], stride NPTS
    float sum = 0.f;
    for (int c8 = 0; c8 < 8; ++c8) {
        bf16x8 hv, mv, lv;
#pragma unroll
        for (int u = 0; u < 8; ++u) {
            float v = xb[(size_t)(c8 * 8 + u) * NPTS];
            sum += v * v;
            unsigned short hb = f2bf_rne(v);
            float r1 = v - bf2f(hb);
            unsigned short mb = f2bf_rne(r1);
            float r2 = r1 - bf2f(mb);
            unsigned short lb = f2bf_rne(r2);
            hv[u] = (short)hb; mv[u] = (short)mb; lv[u] = (short)lb;
        }
        *(bf16x8*)(xs + (size_t)g * 192 + c8 * 8)       = hv;
        *(bf16x8*)(xs + (size_t)g * 192 + 64 + c8 * 8)  = mv;
        *(bf16x8*)(xs + (size_t)g * 192 + 128 + c8 * 8) = lv;
    }
    xx[g] = sum;
}

// ---------------------------------------------------------------------------
// Kernel B: MFMA KNN, two-sweep exact selection. Templated on NSP (column
// splits): grid = 1024*NSP blocks of 1 wave; occupancy scales with NSP.
// Sweep A: MFMA distances + per-lane top-2 per row (registers only).
// Cutoff: U20 = exact 20th of union(per-lane top-2) at 16-bit prefix
// granularity. Sweep B: recompute (bit-identical), append s<=cut via ballot
// ranks; rare bisection-compaction fallback guards CAP.
// Final: wave-wide 64-key bitonic -> exact (s,idx) top-20 per split.
// CAP/TRIG exactness: cnt entering a pass <= TRIG-1 = 31; max 16 appends
// per pass -> cnt <= 47 < CAP=48. MAINTAIN reads slots 0..47 via k0..k2.
// ---------------------------------------------------------------------------
#define CAP       48
#define TRIG      32

template <int NSP>
__global__ __launch_bounds__(64, 4) void knn_mfma_kernel(
    const unsigned short* __restrict__ xs, const float* __restrict__ xx,
    unsigned long long* __restrict__ ptU)
{
    const int SPLITCOLS = NPTS / NSP;
    const int NTILES = SPLITCOLS / 16;

    __shared__ unsigned long long bufU[32][CAP];   // 12.3 KB
    __shared__ int cntL[32];

    int lane = threadIdx.x;
    int cl = lane & 15, grp = lane >> 4;           // grp 0..3 = k-chunk of 8
    int blk = (int)blockIdx.x;
    int b = blk & 7;                    // batch -> XCD affinity
    int rt = blk >> 3;
    int n0 = (rt & 127) * 32;           // row tile within batch
    int split = rt >> 7;                // 0..NSP-1
    int c_base = split * SPLITCOLS;

    const unsigned short* Xb = xs + ((size_t)b << 12) * 192;
    const float* xxb = xx + ((size_t)b << 12);
    int koff = grp * 8;

    // A fragments: rows n0 + h*16 + cl
    bf16x8 aH[2][2], aM[2][2], aL[2][2];
#pragma unroll
    for (int h = 0; h < 2; ++h) {
        const unsigned short* p = Xb + (size_t)(n0 + h * 16 + cl) * 192 + koff;
        aH[h][0] = *(const bf16x8*)(p);
        aH[h][1] = *(const bf16x8*)(p + 32);
        aM[h][0] = *(const bf16x8*)(p + 64);
        aM[h][1] = *(const bf16x8*)(p + 96);
        aL[h][0] = *(const bf16x8*)(p + 128);
        aL[h][1] = *(const bf16x8*)(p + 160);
    }

    bf16x8 B0_[3][2], B1_[3][2];
    float xx0, xx1;

#define LOADB(BF_, XX_, col) do {                                       \
        const unsigned short* p_ = Xb + (size_t)(col) * 192 + koff;     \
        BF_[0][0] = *(const bf16x8*)(p_);                               \
        BF_[0][1] = *(const bf16x8*)(p_ + 32);                          \
        BF_[1][0] = *(const bf16x8*)(p_ + 64);                          \
        BF_[1][1] = *(const bf16x8*)(p_ + 96);                          \
        BF_[2][0] = *(const bf16x8*)(p_ + 128);                         \
        BF_[2][1] = *(const bf16x8*)(p_ + 160);                         \
        XX_ = xxb[col];                                                 \
    } while (0)

#define DOMFMA(B_) \
    f32x4 a00 = {0.f,0.f,0.f,0.f}, a01 = {0.f,0.f,0.f,0.f};             \
    f32x4 a10 = {0.f,0.f,0.f,0.f}, a11 = {0.f,0.f,0.f,0.f};             \
    a00 = MFMA(aH[0][0], B_[0][0], a00);                                \
    a10 = MFMA(aH[1][0], B_[0][0], a10);                                \
    a01 = MFMA(aH[0][1], B_[0][1], a01);                                \
    a11 = MFMA(aH[1][1], B_[0][1], a11);                                \
    a00 = MFMA(aM[0][0], B_[0][0], a00);                                \
    a10 = MFMA(aM[1][0], B_[0][0], a10);                                \
    a01 = MFMA(aM[0][1], B_[0][1], a01);                                \
    a11 = MFMA(aM[1][1], B_[0][1], a11);                                \
    a00 = MFMA(aH[0][0], B_[1][0], a00);                                \
    a10 = MFMA(aH[1][0], B_[1][0], a10);                                \
    a01 = MFMA(aH[0][1], B_[1][1], a01);                                \
    a11 = MFMA(aH[1][1], B_[1][1], a11);                                \
    a00 = MFMA(aM[0][0], B_[1][0], a00);                                \
    a10 = MFMA(aM[1][0], B_[1][0], a10);                                \
    a01 = MFMA(aM[0][1], B_[1][1], a01);                                \
    a11 = MFMA(aM[1][1], B_[1][1], a11);                                \
    a00 = MFMA(aL[0][0], B_[0][0], a00);                                \
    a10 = MFMA(aL[1][0], B_[0][0], a10);                                \
    a01 = MFMA(aL[0][1], B_[0][1], a01);                                \
    a11 = MFMA(aL[1][1], B_[0][1], a11);                                \
    a00 = MFMA(aH[0][0], B_[2][0], a00);                                \
    a10 = MFMA(aH[1][0], B_[2][0], a10);                                \
    a01 = MFMA(aH[0][1], B_[2][1], a01);                                \
    a11 = MFMA(aH[1][1], B_[2][1], a11);

    // ---------------- Sweep A: per-lane top-2 per row -------------------
    float m1[8], m2[8];
#pragma unroll
    for (int q = 0; q < 8; ++q) { m1[q] = FLT_MAX; m2[q] = FLT_MAX; }

#define PROCA(B_, XX_) do {                                             \
    DOMFMA(B_)                                                          \
    _Pragma("unroll")                                                   \
    for (int j = 0; j < 4; ++j) {                                       \
      float d0 = a00[j] + a01[j], d1 = a10[j] + a11[j];                 \
      float s0 = fmaf(-2.f, d0, XX_);                                   \
      float s1 = fmaf(-2.f, d1, XX_);                                   \
      float t0 = fmaxf(m1[j], s0);                                      \
      m1[j] = fminf(m1[j], s0);                                         \
      m2[j] = fminf(m2[j], t0);                                         \
      float t1 = fmaxf(m1[4 + j], s1);                                  \
      m1[4 + j] = fminf(m1[4 + j], s1);                                 \
      m2[4 + j] = fminf(m2[4 + j], t1);                                 \
    }                                                                   \
} while (0)

    LOADB(B0_, xx0, c_base + cl);
    for (int t = 0; t < NTILES; t += 2) {
        LOADB(B1_, xx1, c_base + (t + 1) * 16 + cl);
        PROCA(B0_, xx0);
        if (t + 2 < NTILES) LOADB(B0_, xx0, c_base + (t + 2) * 16 + cl);
        PROCA(B1_, xx1);
    }

    // ------------- cutoff U20: 16-bit-prefix binary search --------------
    float cut[8];
    int   cnt[8];
    {
        unsigned long long gm = 0xFFFFull << (grp << 4);
#pragma unroll
        for (int q = 0; q < 8; ++q) {
            unsigned p1 = flip_f(m1[q]) >> 16;
            unsigned p2 = flip_f(m2[q]) >> 16;
            unsigned lo = 0, hi = 0xFFFFu;
#pragma nounroll
            for (int it = 0; it < 16; ++it) {
                unsigned mid = (lo + hi) >> 1;
                int c2 = (p1 <= mid) + (p2 <= mid);
                unsigned long long bb0 = __ballot((c2 & 1) != 0);
                unsigned long long bb1 = __ballot((c2 & 2) != 0);
                int cc = __popcll(bb0 & gm) + 2 * __popcll(bb1 & gm);
                if (cc >= KNN) hi = mid; else lo = mid + 1;
            }
            cut[q] = (hi == 0xFFFFu) ? FLT_MAX
                                     : unflip_f((hi << 16) | 0xFFFFu);
            cnt[q] = 0;
        }
    }
    bool needm = false;

    // ------------- rare fallback compaction -----------------------------
#define MAINTAIN() do {                                                 \
    _Pragma("unroll")                                                   \
    for (int q = 0; q < 8; ++q) {                                       \
      if (__ballot(cnt[q] >= TRIG)) {                                   \
        bool act = (cnt[q] >= TRIG);                                    \
        int r_ = ((q >> 2) << 4) + (grp << 2) + (q & 3);                \
        if (act) {                                                      \
          int K = cnt[q];                                               \
          unsigned long long k0 = bufU[r_][cl];                         \
          unsigned long long k1 = bufU[r_][cl + 16];                    \
          unsigned long long k2 = (cl + 32 < CAP) ? bufU[r_][cl + 32] : ~0ull; \
          unsigned long long k3 = ~0ull;                                \
          unsigned ps0 = (cl      < K) ? (unsigned)(k0 >> 32) : 0xFFFFFFFFu; \
          unsigned ps1 = (cl + 16 < K) ? (unsigned)(k1 >> 32) : 0xFFFFFFFFu; \
          unsigned ps2 = (cl + 32 < K) ? (unsigned)(k2 >> 32) : 0xFFFFFFFFu; \
          unsigned ps3 = (cl + 48 < K) ? (unsigned)(k3 >> 32) : 0xFFFFFFFFu; \
          unsigned long long gm = 0xFFFFull << (grp << 4);              \
          unsigned lo = 0, hi = 0xFFFFFFFFu, T = 0xFFFFFFFFu;           \
          _Pragma("nounroll")                                           \
          for (int it = 0; it < 34 && lo < hi; ++it) {                  \
            unsigned mid = lo + ((hi - lo) >> 1);                       \
            int c4_ = (ps0 <= mid) + (ps1 <= mid) + (ps2 <= mid) + (ps3 <= mid); \
            unsigned long long bb0 = __ballot((c4_ & 1) != 0);          \
            unsigned long long bb1 = __ballot((c4_ & 2) != 0);          \
            unsigned long long bb2 = __ballot((c4_ & 4) != 0);          \
            int cc = __popcll(bb0 & gm) + 2 * __popcll(bb1 & gm)        \
                   + 4 * __popcll(bb2 & gm);                            \
            if (cc >= KNN && cc <= 31) { T = mid; break; }              \
            if (cc < KNN) lo = mid + 1; else { hi = mid; T = mid; }     \
          }                                                             \
          bool p0 = (cl      < K) && ((unsigned)(k0 >> 32) <= T);       \
          bool p1 = (cl + 16 < K) && ((unsigned)(k1 >> 32) <= T);       \
          bool p2 = (cl + 32 < K) && ((unsigned)(k2 >> 32) <= T);       \
          unsigned long long bq_;                                       \
          bq_ = __ballot(p0); unsigned m0_ = (unsigned)((bq_ >> (grp << 4)) & 0xFFFFull); \
          bq_ = __ballot(p1); unsigned m1_ = (unsigned)((bq_ >> (grp << 4)) & 0xFFFFull); \
          bq_ = __ballot(p2); unsigned m2_ = (unsigned)((bq_ >> (grp << 4)) & 0xFFFFull); \
          int base1 = __popc(m0_), base2 = base1 + __popc(m1_);         \
          int newK = base2 + __popc(m2_);                               \
          unsigned below = (1u << cl) - 1u;                             \
          if (p0) bufU[r_][__popc(m0_ & below)] = k0;                   \
          if (p1) bufU[r_][base1 + __popc(m1_ & below)] = k1;           \
          if (p2) bufU[r_][base2 + __popc(m2_ & below)] = k2;           \
          cnt[q] = newK;                                                \
          cut[q] = unflip_f(T);                                         \
        }                                                               \
      }                                                                 \
    }                                                                   \
} while (0)

    // ---------------- Sweep B: append s <= cut ---------------------------
#define PROCB(B_, XX_, MCOL_) do {                                      \
    DOMFMA(B_)                                                          \
    float s_[8]; bool p_[8];                                            \
    _Pragma("unroll")                                                   \
    for (int j = 0; j < 4; ++j) {                                       \
      float d0 = a00[j] + a01[j], d1 = a10[j] + a11[j];                 \
      s_[j]     = fmaf(-2.f, d0, XX_); p_[j]     = (s_[j]     <= cut[j]);     \
      s_[4 + j] = fmaf(-2.f, d1, XX_); p_[4 + j] = (s_[4 + j] <= cut[4 + j]); \
    }                                                                   \
    bool anyp = p_[0]|p_[1]|p_[2]|p_[3]|p_[4]|p_[5]|p_[6]|p_[7];        \
    if (__ballot(anyp)) {                                               \
      _Pragma("unroll")                                                 \
      for (int q = 0; q < 8; ++q) {                                     \
        unsigned long long bq = __ballot(p_[q]);                        \
        unsigned mq = (unsigned)((bq >> (grp << 4)) & 0xFFFFull);       \
        if (mq) {                                                       \
          int r_ = ((q >> 2) << 4) + (grp << 2) + (q & 3);              \
          int pos = cnt[q] + __popc(mq & ((1u << cl) - 1u));            \
          if (p_[q]) bufU[r_][pos] = pack_key(s_[q], (MCOL_));          \
          cnt[q] += __popc(mq);                                         \
          needm |= (cnt[q] >= TRIG);                                    \
        }                                                               \
      }                                                                 \
      if (__ballot(needm)) { MAINTAIN(); needm = false; }               \
    }                                                                   \
} while (0)

    LOADB(B0_, xx0, c_base + cl);
    for (int t = 0; t < NTILES; t += 2) {
        LOADB(B1_, xx1, c_base + (t + 1) * 16 + cl);
        PROCB(B0_, xx0, c_base + t * 16 + cl);
        if (t + 2 < NTILES) LOADB(B0_, xx0, c_base + (t + 2) * 16 + cl);
        PROCB(B1_, xx1, c_base + (t + 1) * 16 + cl);
    }

    // publish per-row counts
#pragma unroll
    for (int q = 0; q < 8; ++q)
        if (cl == 0) cntL[((q >> 2) << 4) + (grp << 2) + (q & 3)] = cnt[q];
    __syncthreads();

    // final exact per-row top-20: wave-wide bitonic sort of 64 u64 keys
#pragma nounroll
    for (int r = 0; r < 32; ++r) {
        int K = cntL[r];
        if (K > CAP) K = CAP;
        unsigned long long v = (lane < K) ? bufU[r][lane] : ~0ull;
#pragma unroll
        for (int k = 2; k <= 64; k <<= 1) {
#pragma unroll
            for (int j = k >> 1; j > 0; j >>= 1) {
                unsigned long long o = __shfl_xor(v, j);
                bool takeMin = (((lane & j) == 0) == ((lane & k) == 0));
                v = ((v <= o) == takeMin) ? v : o;
            }
        }
        if (lane < KNN)
            ptU[((size_t)split * (NB * NPTS) + ((size_t)b << 12) + (n0 + r)) * KNN + lane] = v;
    }
#undef LOADB
#undef DOMFMA
#undef PROCA
#undef MAINTAIN
#undef PROCB
}

// ---------------------------------------------------------------------------
// Kernel M: merge the NSP sorted top-20 lists per row -> final idx.
// ---------------------------------------------------------------------------
template <int NSP>
__global__ void merge_kernel(const unsigned long long* __restrict__ ptU,
                             int* __restrict__ idxout)
{
    int row = blockIdx.x * 256 + threadIdx.x;      // 0..NB*NPTS-1
    const unsigned long long* L[NSP];
    int p[NSP];
#pragma unroll
    for (int s = 0; s < NSP; ++s) {
        L[s] = ptU + ((size_t)s * (NB * NPTS) + row) * KNN;
        p[s] = 0;
    }
    for (int j = 0; j < KNN; ++j) {
        unsigned long long best = ~0ull; int bs = 0;
#pragma unroll
        for (int s = 0; s < NSP; ++s) {
            unsigned long long k = (p[s] < KNN) ? L[s][p[s]] : ~0ull;
            if (k < best) { best = k; bs = s; }
        }
        ++p[bs];
        idxout[(size_t)row * KNN + j] = (int)(best & 0xffffffffu);
    }
}

// ---------------------------------------------------------------------------
// Kernel A2: per-point y1 = W1*x, y2 = (W2-W1)*x
// ---------------------------------------------------------------------------
__global__ __launch_bounds__(256, 2) void precompute_kernel(
    const float* __restrict__ x, const float* __restrict__ W,
    float* __restrict__ y1, float* __restrict__ y2)
{
    __shared__ float4 wf4[64 * 32];
    int t = threadIdx.x;
    for (int i = 0; i < 8; ++i) {
        int e = t + 256 * i;
        wf4[e] = ((const float4*)W)[e];
    }
    int p = t & 63, og = t >> 6;
    int g = blockIdx.x * 64 + p;
    int b = g >> 12, n = g & 4095;
    const float* xb = x + (size_t)b * NC * NPTS + n;

    float4 xr[16];
#pragma unroll
    for (int c4 = 0; c4 < 16; ++c4) {
        xr[c4].x = xb[(4 * c4 + 0) * NPTS];
        xr[c4].y = xb[(4 * c4 + 1) * NPTS];
        xr[c4].z = xb[(4 * c4 + 2) * NPTS];
        xr[c4].w = xb[(4 * c4 + 3) * NPTS];
    }
    __syncthreads();

    float out1[16], out2[16];
#pragma unroll
    for (int oi = 0; oi < 16; ++oi) {
        int o = og * 16 + oi;
        float a1 = 0.f, a2 = 0.f;
#pragma unroll
        for (int c4 = 0; c4 < 16; ++c4) {
            float4 w1 = wf4[o * 32 + c4];
            float4 w2 = wf4[o * 32 + 16 + c4];
            float4 xv = xr[c4];
            a1 += w1.x * xv.x + w1.y * xv.y + w1.z * xv.z + w1.w * xv.w;
            a2 += w2.x * xv.x + w2.y * xv.y + w2.z * xv.z + w2.w * xv.w;
        }
        out1[oi] = a1;
        out2[oi] = a2 - a1;
    }
    float4* y1p = (float4*)(y1 + (size_t)g * 64 + og * 16);
    float4* y2p = (float4*)(y2 + (size_t)g * 64 + og * 16);
#pragma unroll
    for (int q = 0; q < 4; ++q) {
        y1p[q] = make_float4(out1[4*q], out1[4*q+1], out1[4*q+2], out1[4*q+3]);
        y2p[q] = make_float4(out2[4*q], out2[4*q+1], out2[4*q+2], out2[4*q+3]);
    }
}

// ---------------------------------------------------------------------------
// Kernel C: per-channel sum / sumsq of v = y1[idx] + y2 over (B,N,k).
// ---------------------------------------------------------------------------
__global__ __launch_bounds__(256, 4) void stats_kernel(
    const float* __restrict__ y1, const float* __restrict__ y2,
    const int* __restrict__ idx, float* __restrict__ part)
{
    int t = threadIdx.x;
    int o = t & 63, p4 = t >> 6;
    int blk = (int)blockIdx.x;
    int g0 = ((blk & 7) * 64 + (blk >> 3)) * 64;   // batch-per-XCD swizzle
    float s1 = 0.f, s2 = 0.f;
    for (int pi = 0; pi < 16; ++pi) {
        int g = g0 + pi * 4 + p4;
        int b = g >> 12;
        float y2v = y2[(size_t)g * 64 + o];
        const int* ip = idx + (size_t)g * KNN;
#pragma unroll
        for (int j = 0; j < KNN; ++j) {
            int id = ip[j];
            float v = y1[((size_t)(b << 12) + id) * 64 + o] + y2v;
            s1 += v; s2 += v * v;
        }
    }
    __shared__ float red[256];
    red[t] = s1; __syncthreads();
    if (t < 64) part[blockIdx.x * 128 + o] = red[o] + red[64 + o] + red[128 + o] + red[192 + o];
    __syncthreads();
    red[t] = s2; __syncthreads();
    if (t < 64) part[blockIdx.x * 128 + 64 + o] = red[o] + red[64 + o] + red[128 + o] + red[192 + o];
}

__global__ void finalize_stats_kernel(
    const float* __restrict__ part, const float* __restrict__ gamma,
    const float* __restrict__ beta, float* __restrict__ ss)
{
    int t = threadIdx.x;   // 128 threads
    float S = 0.f;
    for (int p = 0; p < 512; ++p) S += part[p * 128 + t];
    __shared__ float sm[128];
    sm[t] = S; __syncthreads();
    if (t < 64) {
        const float inv = 1.f / (float)(NB * NPTS * KNN);
        float mean = sm[t] * inv;
        float var  = sm[64 + t] * inv - mean * mean;
        float scale = gamma[t] * rsqrtf(var + 1e-5f);
        ss[t] = scale;
        ss[64 + t] = beta[t] - mean * scale;
    }
}

// ---------------------------------------------------------------------------
// Kernel E: max/min over k, affine+relu, transpose, write out[b][o][n].
// ---------------------------------------------------------------------------
__global__ __launch_bounds__(256, 4) void epilogue_kernel(
    const float* __restrict__ y1, const float* __restrict__ y2,
    const int* __restrict__ idx, const float* __restrict__ ss,
    float* __restrict__ out)
{
    __shared__ float zT[64][65];
    int t = threadIdx.x;
    int o = t & 63, p4 = t >> 6;
    float sc = ss[o], sh = ss[64 + o];
    int blk = (int)blockIdx.x;
    int g0 = ((blk & 7) * 64 + (blk >> 3)) * 64;   // batch-per-XCD swizzle
    int b = g0 >> 12, n0 = g0 & 4095;
    for (int pi = 0; pi < 16; ++pi) {
        int pc = pi * 4 + p4;
        int g = g0 + pc;
        float y2v = y2[(size_t)g * 64 + o];
        const int* ip = idx + (size_t)g * KNN;
        float vmax = -FLT_MAX, vmin = FLT_MAX;
#pragma unroll
        for (int j = 0; j < KNN; ++j) {
            int id = ip[j];
            float v = y1[((size_t)(b << 12) + id) * 64 + o] + y2v;
            vmax = fmaxf(vmax, v); vmin = fminf(vmin, v);
        }
        float z = (sc >= 0.f) ? sc * vmax + sh : sc * vmin + sh;
        zT[o][pc] = fmaxf(z, 0.f);
    }
    __syncthreads();
    for (int i = 0; i < 16; ++i) {
        int e = t + 256 * i;
        int oo = e >> 6, nn = e & 63;
        out[((size_t)(b * 64 + oo)) * 4096 + n0 + nn] = zT[oo][nn];
    }
}

// ---------------------------------------------------------------------------
extern "C" void kernel_launch(void* const* d_in, const int* in_sizes, int n_in,
                              void* d_out, int out_size, void* d_ws, size_t ws_size,
                              hipStream_t stream)
{
    const float* x     = (const float*)d_in[0];
    const float* W     = (const float*)d_in[1];
    const float* gamma = (const float*)d_in[2];
    const float* beta  = (const float*)d_in[3];
    float* out = (float*)d_out;

    char* ws = (char*)d_ws;
    unsigned short* xs = (unsigned short*)(ws);                     // 12 MB
    unsigned long long* ptU = (unsigned long long*)(ws + 12582912);

    // NSP=4 needs: 12582912 + 4*32768*160 + 2621440 + 131072 + 262144 + 512
    const size_t need4 = 12582912ull + 20971520ull + 2621440ull + 131072ull
                       + 262144ull + 512ull;                        // ~34.9 MB
    const bool big = (ws_size >= need4);
    const size_t ptU_bytes = (big ? 4ull : 2ull) * NB * NPTS * KNN * 8ull;

    char* tail = ws + 12582912 + ptU_bytes;
    int*   idx  = (int*)  (tail);
    float* xx   = (float*)(tail + 2621440);
    float* part = (float*)(tail + 2621440 + 131072);
    float* ss   = (float*)(tail + 2621440 + 131072 + 262144);
    // phase 2 overlays phase-1 region (xs+ptU dead after merge)
    float* y1   = (float*)(ws);                                     // 8 MB
    float* y2   = (float*)(ws + 8388608);                           // 8 MB

    hipLaunchKernelGGL(split_kernel, dim3(128), dim3(256), 0, stream, x, xs, xx);
    if (big) {
        hipLaunchKernelGGL((knn_mfma_kernel<4>), dim3(4096), dim3(64), 0, stream, xs, xx, ptU);
        hipLaunchKernelGGL((merge_kernel<4>),    dim3(128),  dim3(256), 0, stream, ptU, idx);
    } else {
        hipLaunchKernelGGL((knn_mfma_kernel<2>), dim3(2048), dim3(64), 0, stream, xs, xx, ptU);
        hipLaunchKernelGGL((merge_kernel<2>),    dim3(128),  dim3(256), 0, stream, ptU, idx);
    }
    hipLaunchKernelGGL(precompute_kernel,     dim3(512),  dim3(256), 0, stream, x, W, y1, y2);
    hipLaunchKernelGGL(stats_kernel,          dim3(512),  dim3(256), 0, stream, y1, y2, idx, part);
    hipLaunchKernelGGL(finalize_stats_kernel, dim3(1),    dim3(128), 0, stream, part, gamma, beta, ss);
    hipLaunchKernelGGL(epilogue_kernel,       dim3(512),  dim3(256), 0, stream, y1, y2, idx, ss, out);
}

// Round 6
// 433.033 us; speedup vs baseline: 2.4640x; 2.4640x over previous
//
#include <hip/hip_runtime.h>
#include <cfloat>

#define NB   8
#define NC   64
#define NPTS 4096
#define KNN  20
#define CO   64

typedef __attribute__((ext_vector_type(8))) short bf16x8;
typedef __attribute__((ext_vector_type(4))) float f32x4;

#define MFMA(a, b, c) __builtin_amdgcn_mfma_f32_16x16x32_bf16(a, b, c, 0, 0, 0)
#define SB0() __builtin_amdgcn_sched_barrier(0)

// ---------------------------------------------------------------------------
// bf16 helpers (RNE, bit-level; no NaN in this workload)
// ---------------------------------------------------------------------------
__device__ __forceinline__ unsigned short f2bf_rne(float f) {
    unsigned int u = __float_as_uint(f);
    unsigned int r = (u + 0x7FFFu + ((u >> 16) & 1u)) >> 16;
    return (unsigned short)r;
}
__device__ __forceinline__ float bf2f(unsigned short h) {
    return __uint_as_float(((unsigned int)h) << 16);
}

// monotone f32 <-> u32 order-preserving transform
__device__ __forceinline__ unsigned int flip_f(float s) {
    unsigned int b = __float_as_uint(s);
    return (b & 0x80000000u) ? ~b : (b | 0x80000000u);
}
__device__ __forceinline__ float unflip_f(unsigned int u) {
    unsigned int b = (u & 0x80000000u) ? (u ^ 0x80000000u) : ~u;
    return __uint_as_float(b);
}
// key packing: lexicographic (s, idx) ascending == u64 ascending
__device__ __forceinline__ unsigned long long pack_key(float s, int m) {
    return (((unsigned long long)flip_f(s)) << 32) | (unsigned int)m;
}

// ---------------------------------------------------------------------------
// Kernel P1: split x into bf16 triple (h,m,l), INTERLEAVED per point:
// xs[g][0..63]=h, [64..127]=m, [128..191]=l.  x = h+m+l+eps, |eps|<=2^-27|x|.
// ---------------------------------------------------------------------------
__global__ __launch_bounds__(256, 4) void split_kernel(
    const float* __restrict__ x, unsigned short* __restrict__ xs,
    float* __restrict__ xx)
{
    int g = blockIdx.x * 256 + threadIdx.x;        // global point
    int b = g >> 12, n = g & 4095;
    const float* xb = x + ((size_t)b << 18) + n;   // x[b][c][n], stride NPTS
    float sum = 0.f;
    for (int c8 = 0; c8 < 8; ++c8) {
        bf16x8 hv, mv, lv;
#pragma unroll
        for (int u = 0; u < 8; ++u) {
            float v = xb[(size_t)(c8 * 8 + u) * NPTS];
            sum += v * v;
            unsigned short hb = f2bf_rne(v);
            float r1 = v - bf2f(hb);
            unsigned short mb = f2bf_rne(r1);
            float r2 = r1 - bf2f(mb);
            unsigned short lb = f2bf_rne(r2);
            hv[u] = (short)hb; mv[u] = (short)mb; lv[u] = (short)lb;
        }
        *(bf16x8*)(xs + (size_t)g * 192 + c8 * 8)       = hv;
        *(bf16x8*)(xs + (size_t)g * 192 + 64 + c8 * 8)  = mv;
        *(bf16x8*)(xs + (size_t)g * 192 + 128 + c8 * 8) = lv;
    }
    xx[g] = sum;
}

// ---------------------------------------------------------------------------
// Kernel B: MFMA KNN, two-sweep selection.
// Sweep A (approx): h-only product, per-lane top-2 per row, 3-deep pipelined.
// Cutoff: U20_h (binary search on 16-bit prefixes) + SLACK, where SLACK
// bounds |s_exact - s_h| (<= 2*sqrt(xx_n*xx_m)*2^-8 <= 0.94 here; use 2.0).
// Sweep B (exact): 6-product f32-exact s, append s<=cut via ballot ranks,
// sched_barrier(0)-pinned register double-buffer; bisection-compaction
// fallback guards CAP. Final: wave-wide 64-key bitonic -> exact top-20.
// CAP/TRIG exactness: cnt entering a pass <= TRIG-1 = 31; max 16 appends
// per pass -> cnt <= 47 < CAP=48.
// ---------------------------------------------------------------------------
#define NSPLIT    2
#define SPLITCOLS (NPTS / NSPLIT)     // 2048
#define NTILES    (SPLITCOLS / 16)    // 128
#define CAP       48
#define TRIG      32
#define SLACK     2.0f

__global__ __launch_bounds__(64, 2) void knn_mfma_kernel(
    const unsigned short* __restrict__ xs, const float* __restrict__ xx,
    unsigned long long* __restrict__ ptU)
{
    __shared__ unsigned long long bufU[32][CAP];   // 12.3 KB
    __shared__ int cntL[32];

    int lane = threadIdx.x;
    int cl = lane & 15, grp = lane >> 4;           // grp 0..3 = k-chunk of 8
    int blk = (int)blockIdx.x;
    int b = blk & 7;                    // batch -> XCD affinity
    int rt = blk >> 3;
    int n0 = (rt & 127) * 32;           // row tile within batch
    int split = rt >> 7;                // 0..NSPLIT-1
    int c_base = split * SPLITCOLS;

    const unsigned short* Xb = xs + ((size_t)b << 12) * 192;
    const float* xxb = xx + ((size_t)b << 12);
    int koff = grp * 8;

    // A fragments: rows n0 + h*16 + cl
    bf16x8 aH[2][2], aM[2][2], aL[2][2];
#pragma unroll
    for (int h = 0; h < 2; ++h) {
        const unsigned short* p = Xb + (size_t)(n0 + h * 16 + cl) * 192 + koff;
        aH[h][0] = *(const bf16x8*)(p);
        aH[h][1] = *(const bf16x8*)(p + 32);
        aM[h][0] = *(const bf16x8*)(p + 64);
        aM[h][1] = *(const bf16x8*)(p + 96);
        aL[h][0] = *(const bf16x8*)(p + 128);
        aL[h][1] = *(const bf16x8*)(p + 160);
    }

    // ---------------- Sweep A: h-only, per-lane top-2 per row ------------
    float m1[8], m2[8];
#pragma unroll
    for (int q = 0; q < 8; ++q) { m1[q] = FLT_MAX; m2[q] = FLT_MAX; }

#define LOADH(HF_, XX_, col) do {                                       \
        const unsigned short* p_ = Xb + (size_t)(col) * 192 + koff;     \
        HF_[0] = *(const bf16x8*)(p_);                                  \
        HF_[1] = *(const bf16x8*)(p_ + 32);                             \
        XX_ = xxb[col];                                                 \
    } while (0)

#define PROCA(HF_, XX_) do {                                            \
    f32x4 a00 = {0.f,0.f,0.f,0.f}, a01 = {0.f,0.f,0.f,0.f};             \
    f32x4 a10 = {0.f,0.f,0.f,0.f}, a11 = {0.f,0.f,0.f,0.f};             \
    a00 = MFMA(aH[0][0], HF_[0], a00);                                  \
    a10 = MFMA(aH[1][0], HF_[0], a10);                                  \
    a01 = MFMA(aH[0][1], HF_[1], a01);                                  \
    a11 = MFMA(aH[1][1], HF_[1], a11);                                  \
    _Pragma("unroll")                                                   \
    for (int j = 0; j < 4; ++j) {                                       \
      float d0 = a00[j] + a01[j], d1 = a10[j] + a11[j];                 \
      float s0 = fmaf(-2.f, d0, XX_);                                   \
      float s1 = fmaf(-2.f, d1, XX_);                                   \
      float t0 = fmaxf(m1[j], s0);                                      \
      m1[j] = fminf(m1[j], s0);                                         \
      m2[j] = fminf(m2[j], t0);                                         \
      float t1 = fmaxf(m1[4 + j], s1);                                  \
      m1[4 + j] = fminf(m1[4 + j], s1);                                 \
      m2[4 + j] = fminf(m2[4 + j], t1);                                 \
    }                                                                   \
} while (0)

    {
        bf16x8 h0[2], h1[2], h2[2], h3[2];
        float xa0, xa1, xa2, xa3;
        LOADH(h0, xa0, c_base + 0 * 16 + cl);
        LOADH(h1, xa1, c_base + 1 * 16 + cl);
        LOADH(h2, xa2, c_base + 2 * 16 + cl);
        for (int t = 0; t < NTILES; t += 4) {
            LOADH(h3, xa3, c_base + (t + 3) * 16 + cl);
            SB0();
            PROCA(h0, xa0);
            if (t + 4 < NTILES) LOADH(h0, xa0, c_base + (t + 4) * 16 + cl);
            SB0();
            PROCA(h1, xa1);
            if (t + 5 < NTILES) LOADH(h1, xa1, c_base + (t + 5) * 16 + cl);
            SB0();
            PROCA(h2, xa2);
            if (t + 6 < NTILES) LOADH(h2, xa2, c_base + (t + 6) * 16 + cl);
            SB0();
            PROCA(h3, xa3);
        }
    }

    // ------------- cutoff U20_h + SLACK: 16-bit-prefix binary search ----
    float cut[8];
    int   cnt[8];
    {
        unsigned long long gm = 0xFFFFull << (grp << 4);
#pragma unroll
        for (int q = 0; q < 8; ++q) {
            unsigned p1 = flip_f(m1[q]) >> 16;
            unsigned p2 = flip_f(m2[q]) >> 16;
            unsigned lo = 0, hi = 0xFFFFu;
#pragma nounroll
            for (int it = 0; it < 16; ++it) {
                unsigned mid = (lo + hi) >> 1;
                int c2 = (p1 <= mid) + (p2 <= mid);
                unsigned long long bb0 = __ballot((c2 & 1) != 0);
                unsigned long long bb1 = __ballot((c2 & 2) != 0);
                int cc = __popcll(bb0 & gm) + 2 * __popcll(bb1 & gm);
                if (cc >= KNN) hi = mid; else lo = mid + 1;
            }
            cut[q] = (hi == 0xFFFFu) ? FLT_MAX
                                     : unflip_f((hi << 16) | 0xFFFFu) + SLACK;
            cnt[q] = 0;
        }
    }
    bool needm = false;

    bf16x8 B0_[3][2], B1_[3][2];
    float xx0, xx1;

#define LOADB(BF_, XX_, col) do {                                       \
        const unsigned short* p_ = Xb + (size_t)(col) * 192 + koff;     \
        BF_[0][0] = *(const bf16x8*)(p_);                               \
        BF_[0][1] = *(const bf16x8*)(p_ + 32);                          \
        BF_[1][0] = *(const bf16x8*)(p_ + 64);                          \
        BF_[1][1] = *(const bf16x8*)(p_ + 96);                          \
        BF_[2][0] = *(const bf16x8*)(p_ + 128);                         \
        BF_[2][1] = *(const bf16x8*)(p_ + 160);                         \
        XX_ = xxb[col];                                                 \
    } while (0)

#define DOMFMA(B_) \
    f32x4 a00 = {0.f,0.f,0.f,0.f}, a01 = {0.f,0.f,0.f,0.f};             \
    f32x4 a10 = {0.f,0.f,0.f,0.f}, a11 = {0.f,0.f,0.f,0.f};             \
    a00 = MFMA(aH[0][0], B_[0][0], a00);                                \
    a10 = MFMA(aH[1][0], B_[0][0], a10);                                \
    a01 = MFMA(aH[0][1], B_[0][1], a01);                                \
    a11 = MFMA(aH[1][1], B_[0][1], a11);                                \
    a00 = MFMA(aM[0][0], B_[0][0], a00);                                \
    a10 = MFMA(aM[1][0], B_[0][0], a10);                                \
    a01 = MFMA(aM[0][1], B_[0][1], a01);                                \
    a11 = MFMA(aM[1][1], B_[0][1], a11);                                \
    a00 = MFMA(aH[0][0], B_[1][0], a00);                                \
    a10 = MFMA(aH[1][0], B_[1][0], a10);                                \
    a01 = MFMA(aH[0][1], B_[1][1], a01);                                \
    a11 = MFMA(aH[1][1], B_[1][1], a11);                                \
    a00 = MFMA(aM[0][0], B_[1][0], a00);                                \
    a10 = MFMA(aM[1][0], B_[1][0], a10);                                \
    a01 = MFMA(aM[0][1], B_[1][1], a01);                                \
    a11 = MFMA(aM[1][1], B_[1][1], a11);                                \
    a00 = MFMA(aL[0][0], B_[0][0], a00);                                \
    a10 = MFMA(aL[1][0], B_[0][0], a10);                                \
    a01 = MFMA(aL[0][1], B_[0][1], a01);                                \
    a11 = MFMA(aL[1][1], B_[0][1], a11);                                \
    a00 = MFMA(aH[0][0], B_[2][0], a00);                                \
    a10 = MFMA(aH[1][0], B_[2][0], a10);                                \
    a01 = MFMA(aH[0][1], B_[2][1], a01);                                \
    a11 = MFMA(aH[1][1], B_[2][1], a11);

    // ------------- rare fallback compaction -----------------------------
#define MAINTAIN() do {                                                 \
    _Pragma("unroll")                                                   \
    for (int q = 0; q < 8; ++q) {                                       \
      if (__ballot(cnt[q] >= TRIG)) {                                   \
        bool act = (cnt[q] >= TRIG);                                    \
        int r_ = ((q >> 2) << 4) + (grp << 2) + (q & 3);                \
        if (act) {                                                      \
          int K = cnt[q];                                               \
          unsigned long long k0 = bufU[r_][cl];                         \
          unsigned long long k1 = bufU[r_][cl + 16];                    \
          unsigned long long k2 = (cl + 32 < CAP) ? bufU[r_][cl + 32] : ~0ull; \
          unsigned ps0 = (cl      < K) ? (unsigned)(k0 >> 32) : 0xFFFFFFFFu; \
          unsigned ps1 = (cl + 16 < K) ? (unsigned)(k1 >> 32) : 0xFFFFFFFFu; \
          unsigned ps2 = (cl + 32 < K) ? (unsigned)(k2 >> 32) : 0xFFFFFFFFu; \
          unsigned long long gm = 0xFFFFull << (grp << 4);              \
          unsigned lo = 0, hi = 0xFFFFFFFFu, T = 0xFFFFFFFFu;           \
          _Pragma("nounroll")                                           \
          for (int it = 0; it < 34 && lo < hi; ++it) {                  \
            unsigned mid = lo + ((hi - lo) >> 1);                       \
            int c4_ = (ps0 <= mid) + (ps1 <= mid) + (ps2 <= mid);       \
            unsigned long long bb0 = __ballot((c4_ & 1) != 0);          \
            unsigned long long bb1 = __ballot((c4_ & 2) != 0);          \
            int cc = __popcll(bb0 & gm) + 2 * __popcll(bb1 & gm);       \
            if (cc >= KNN && cc <= 31) { T = mid; break; }              \
            if (cc < KNN) lo = mid + 1; else { hi = mid; T = mid; }     \
          }                                                             \
          bool p0 = (cl      < K) && ((unsigned)(k0 >> 32) <= T);       \
          bool p1 = (cl + 16 < K) && ((unsigned)(k1 >> 32) <= T);       \
          bool p2 = (cl + 32 < K) && ((unsigned)(k2 >> 32) <= T);       \
          unsigned long long bq_;                                       \
          bq_ = __ballot(p0); unsigned m0_ = (unsigned)((bq_ >> (grp << 4)) & 0xFFFFull); \
          bq_ = __ballot(p1); unsigned m1_ = (unsigned)((bq_ >> (grp << 4)) & 0xFFFFull); \
          bq_ = __ballot(p2); unsigned m2_ = (unsigned)((bq_ >> (grp << 4)) & 0xFFFFull); \
          int base1 = __popc(m0_), base2 = base1 + __popc(m1_);         \
          int newK = base2 + __popc(m2_);                               \
          unsigned below = (1u << cl) - 1u;                             \
          if (p0) bufU[r_][__popc(m0_ & below)] = k0;                   \
          if (p1) bufU[r_][base1 + __popc(m1_ & below)] = k1;           \
          if (p2) bufU[r_][base2 + __popc(m2_ & below)] = k2;           \
          cnt[q] = newK;                                                \
          cut[q] = unflip_f(T);                                         \
        }                                                               \
      }                                                                 \
    }                                                                   \
} while (0)

    // ---------------- Sweep B: append s <= cut ---------------------------
#define PROCB(B_, XX_, MCOL_) do {                                      \
    DOMFMA(B_)                                                          \
    float s_[8]; bool p_[8];                                            \
    _Pragma("unroll")                                                   \
    for (int j = 0; j < 4; ++j) {                                       \
      float d0 = a00[j] + a01[j], d1 = a10[j] + a11[j];                 \
      s_[j]     = fmaf(-2.f, d0, XX_); p_[j]     = (s_[j]     <= cut[j]);     \
      s_[4 + j] = fmaf(-2.f, d1, XX_); p_[4 + j] = (s_[4 + j] <= cut[4 + j]); \
    }                                                                   \
    bool anyp = p_[0]|p_[1]|p_[2]|p_[3]|p_[4]|p_[5]|p_[6]|p_[7];        \
    if (__ballot(anyp)) {                                               \
      _Pragma("unroll")                                                 \
      for (int q = 0; q < 8; ++q) {                                     \
        unsigned long long bq = __ballot(p_[q]);                        \
        unsigned mq = (unsigned)((bq >> (grp << 4)) & 0xFFFFull);       \
        if (mq) {                                                       \
          int r_ = ((q >> 2) << 4) + (grp << 2) + (q & 3);              \
          int pos = cnt[q] + __popc(mq & ((1u << cl) - 1u));            \
          if (p_[q]) bufU[r_][pos] = pack_key(s_[q], (MCOL_));          \
          cnt[q] += __popc(mq);                                         \
          needm |= (cnt[q] >= TRIG);                                    \
        }                                                               \
      }                                                                 \
      if (__ballot(needm)) { MAINTAIN(); needm = false; }               \
    }                                                                   \
} while (0)

    LOADB(B0_, xx0, c_base + cl);
    for (int t = 0; t < NTILES; t += 2) {
        LOADB(B1_, xx1, c_base + (t + 1) * 16 + cl);
        SB0();
        PROCB(B0_, xx0, c_base + t * 16 + cl);
        if (t + 2 < NTILES) LOADB(B0_, xx0, c_base + (t + 2) * 16 + cl);
        SB0();
        PROCB(B1_, xx1, c_base + (t + 1) * 16 + cl);
    }

    // publish per-row counts
#pragma unroll
    for (int q = 0; q < 8; ++q)
        if (cl == 0) cntL[((q >> 2) << 4) + (grp << 2) + (q & 3)] = cnt[q];
    __syncthreads();

    // final exact per-row top-20: wave-wide bitonic sort of 64 u64 keys
#pragma nounroll
    for (int r = 0; r < 32; ++r) {
        int K = cntL[r];
        if (K > CAP) K = CAP;
        unsigned long long v = (lane < K) ? bufU[r][lane] : ~0ull;
#pragma unroll
        for (int k = 2; k <= 64; k <<= 1) {
#pragma unroll
            for (int j = k >> 1; j > 0; j >>= 1) {
                unsigned long long o = __shfl_xor(v, j);
                bool takeMin = (((lane & j) == 0) == ((lane & k) == 0));
                v = ((v <= o) == takeMin) ? v : o;
            }
        }
        if (lane < KNN)
            ptU[((size_t)split * (NB * NPTS) + ((size_t)b << 12) + (n0 + r)) * KNN + lane] = v;
    }
#undef LOADH
#undef PROCA
#undef LOADB
#undef DOMFMA
#undef MAINTAIN
#undef PROCB
}

// ---------------------------------------------------------------------------
// Kernel M: merge the 2 sorted top-20 lists per row -> final idx.
// ---------------------------------------------------------------------------
__global__ void merge_kernel(const unsigned long long* __restrict__ ptU,
                             int* __restrict__ idxout)
{
    int row = blockIdx.x * 256 + threadIdx.x;      // 0..NB*NPTS-1
    const unsigned long long* A = ptU + (size_t)row * KNN;
    const unsigned long long* B = ptU + ((size_t)(NB * NPTS) + row) * KNN;
    int ia = 0, ib = 0;
    for (int j = 0; j < KNN; ++j) {
        unsigned long long ka = (ia < KNN) ? A[ia] : ~0ull;
        unsigned long long kb = (ib < KNN) ? B[ib] : ~0ull;
        if (ka < kb) { idxout[(size_t)row * KNN + j] = (int)(ka & 0xffffffffu); ++ia; }
        else         { idxout[(size_t)row * KNN + j] = (int)(kb & 0xffffffffu); ++ib; }
    }
}

// ---------------------------------------------------------------------------
// Kernel A2: per-point y1 = W1*x, y2 = (W2-W1)*x
// ---------------------------------------------------------------------------
__global__ __launch_bounds__(256, 2) void precompute_kernel(
    const float* __restrict__ x, const float* __restrict__ W,
    float* __restrict__ y1, float* __restrict__ y2)
{
    __shared__ float4 wf4[64 * 32];
    int t = threadIdx.x;
    for (int i = 0; i < 8; ++i) {
        int e = t + 256 * i;
        wf4[e] = ((const float4*)W)[e];
    }
    int p = t & 63, og = t >> 6;
    int g = blockIdx.x * 64 + p;
    int b = g >> 12, n = g & 4095;
    const float* xb = x + (size_t)b * NC * NPTS + n;

    float4 xr[16];
#pragma unroll
    for (int c4 = 0; c4 < 16; ++c4) {
        xr[c4].x = xb[(4 * c4 + 0) * NPTS];
        xr[c4].y = xb[(4 * c4 + 1) * NPTS];
        xr[c4].z = xb[(4 * c4 + 2) * NPTS];
        xr[c4].w = xb[(4 * c4 + 3) * NPTS];
    }
    __syncthreads();

    float out1[16], out2[16];
#pragma unroll
    for (int oi = 0; oi < 16; ++oi) {
        int o = og * 16 + oi;
        float a1 = 0.f, a2 = 0.f;
#pragma unroll
        for (int c4 = 0; c4 < 16; ++c4) {
            float4 w1 = wf4[o * 32 + c4];
            float4 w2 = wf4[o * 32 + 16 + c4];
            float4 xv = xr[c4];
            a1 += w1.x * xv.x + w1.y * xv.y + w1.z * xv.z + w1.w * xv.w;
            a2 += w2.x * xv.x + w2.y * xv.y + w2.z * xv.z + w2.w * xv.w;
        }
        out1[oi] = a1;
        out2[oi] = a2 - a1;
    }
    float4* y1p = (float4*)(y1 + (size_t)g * 64 + og * 16);
    float4* y2p = (float4*)(y2 + (size_t)g * 64 + og * 16);
#pragma unroll
    for (int q = 0; q < 4; ++q) {
        y1p[q] = make_float4(out1[4*q], out1[4*q+1], out1[4*q+2], out1[4*q+3]);
        y2p[q] = make_float4(out2[4*q], out2[4*q+1], out2[4*q+2], out2[4*q+3]);
    }
}

// ---------------------------------------------------------------------------
// Kernel C: per-channel sum / sumsq of v = y1[idx] + y2 over (B,N,k).
// ---------------------------------------------------------------------------
__global__ __launch_bounds__(256, 4) void stats_kernel(
    const float* __restrict__ y1, const float* __restrict__ y2,
    const int* __restrict__ idx, float* __restrict__ part)
{
    int t = threadIdx.x;
    int o = t & 63, p4 = t >> 6;
    int blk = (int)blockIdx.x;
    int g0 = ((blk & 7) * 64 + (blk >> 3)) * 64;   // batch-per-XCD swizzle
    float s1 = 0.f, s2 = 0.f;
    for (int pi = 0; pi < 16; ++pi) {
        int g = g0 + pi * 4 + p4;
        int b = g >> 12;
        float y2v = y2[(size_t)g * 64 + o];
        const int* ip = idx + (size_t)g * KNN;
#pragma unroll
        for (int j = 0; j < KNN; ++j) {
            int id = ip[j];
            float v = y1[((size_t)(b << 12) + id) * 64 + o] + y2v;
            s1 += v; s2 += v * v;
        }
    }
    __shared__ float red[256];
    red[t] = s1; __syncthreads();
    if (t < 64) part[blockIdx.x * 128 + o] = red[o] + red[64 + o] + red[128 + o] + red[192 + o];
    __syncthreads();
    red[t] = s2; __syncthreads();
    if (t < 64) part[blockIdx.x * 128 + 64 + o] = red[o] + red[64 + o] + red[128 + o] + red[192 + o];
}

__global__ void finalize_stats_kernel(
    const float* __restrict__ part, const float* __restrict__ gamma,
    const float* __restrict__ beta, float* __restrict__ ss)
{
    int t = threadIdx.x;   // 128 threads
    float S = 0.f;
    for (int p = 0; p < 512; ++p) S += part[p * 128 + t];
    __shared__ float sm[128];
    sm[t] = S; __syncthreads();
    if (t < 64) {
        const float inv = 1.f / (float)(NB * NPTS * KNN);
        float mean = sm[t] * inv;
        float var  = sm[64 + t] * inv - mean * mean;
        float scale = gamma[t] * rsqrtf(var + 1e-5f);
        ss[t] = scale;
        ss[64 + t] = beta[t] - mean * scale;
    }
}

// ---------------------------------------------------------------------------
// Kernel E: max/min over k, affine+relu, transpose, write out[b][o][n].
// ---------------------------------------------------------------------------
__global__ __launch_bounds__(256, 4) void epilogue_kernel(
    const float* __restrict__ y1, const float* __restrict__ y2,
    const int* __restrict__ idx, const float* __restrict__ ss,
    float* __restrict__ out)
{
    __shared__ float zT[64][65];
    int t = threadIdx.x;
    int o = t & 63, p4 = t >> 6;
    float sc = ss[o], sh = ss[64 + o];
    int blk = (int)blockIdx.x;
    int g0 = ((blk & 7) * 64 + (blk >> 3)) * 64;   // batch-per-XCD swizzle
    int b = g0 >> 12, n0 = g0 & 4095;
    for (int pi = 0; pi < 16; ++pi) {
        int pc = pi * 4 + p4;
        int g = g0 + pc;
        float y2v = y2[(size_t)g * 64 + o];
        const int* ip = idx + (size_t)g * KNN;
        float vmax = -FLT_MAX, vmin = FLT_MAX;
#pragma unroll
        for (int j = 0; j < KNN; ++j) {
            int id = ip[j];
            float v = y1[((size_t)(b << 12) + id) * 64 + o] + y2v;
            vmax = fmaxf(vmax, v); vmin = fminf(vmin, v);
        }
        float z = (sc >= 0.f) ? sc * vmax + sh : sc * vmin + sh;
        zT[o][pc] = fmaxf(z, 0.f);
    }
    __syncthreads();
    for (int i = 0; i < 16; ++i) {
        int e = t + 256 * i;
        int oo = e >> 6, nn = e & 63;
        out[((size_t)(b * 64 + oo)) * 4096 + n0 + nn] = zT[oo][nn];
    }
}

// ---------------------------------------------------------------------------
extern "C" void kernel_launch(void* const* d_in, const int* in_sizes, int n_in,
                              void* d_out, int out_size, void* d_ws, size_t ws_size,
                              hipStream_t stream)
{
    const float* x     = (const float*)d_in[0];
    const float* W     = (const float*)d_in[1];
    const float* gamma = (const float*)d_in[2];
    const float* beta  = (const float*)d_in[3];
    float* out = (float*)d_out;

    char* ws = (char*)d_ws;
    // phase 1 (dead after merge): xs (12 MB) + ptU (10.49 MB)
    unsigned short* xs = (unsigned short*)(ws);                     // 12 MB
    unsigned long long* ptU = (unsigned long long*)(ws + 12582912);
    // persistent
    int*   idx  = (int*)  (ws + 23068672);                          // 2.62 MB
    float* xx   = (float*)(ws + 25690112);                          // 128 KB
    float* part = (float*)(ws + 25821184);                          // 256 KB
    float* ss   = (float*)(ws + 26083328);                          // 512 B
    // phase 2 overlays phase-1 region (xs+ptU dead after merge)
    float* y1   = (float*)(ws);                                     // 8 MB
    float* y2   = (float*)(ws + 8388608);                           // 8 MB

    hipLaunchKernelGGL(split_kernel,          dim3(128),  dim3(256), 0, stream, x, xs, xx);
    hipLaunchKernelGGL(knn_mfma_kernel,       dim3(2048), dim3(64),  0, stream, xs, xx, ptU);
    hipLaunchKernelGGL(merge_kernel,          dim3(128),  dim3(256), 0, stream, ptU, idx);
    hipLaunchKernelGGL(precompute_kernel,     dim3(512),  dim3(256), 0, stream, x, W, y1, y2);
    hipLaunchKernelGGL(stats_kernel,          dim3(512),  dim3(256), 0, stream, y1, y2, idx, part);
    hipLaunchKernelGGL(finalize_stats_kernel, dim3(1),    dim3(128), 0, stream, part, gamma, beta, ss);
    hipLaunchKernelGGL(epilogue_kernel,       dim3(512),  dim3(256), 0, stream, y1, y2, idx, ss, out);
}